// Round 19
// baseline (371.146 us; speedup 1.0000x reference)
//
#include <hip/hip_runtime.h>
#include <hip/hip_fp16.h>

#define DIM 256
#define MAXMEM 16
#define MAXDEG 288

typedef _Float16 f16x8 __attribute__((ext_vector_type(8)));
typedef float f32x4 __attribute__((ext_vector_type(4)));

__device__ inline unsigned short f2h(float f) {
  return __half_as_ushort(__float2half_rn(f));
}
__device__ inline float h2f(unsigned short u) {
  return __half2float(__ushort_as_half(u));
}
__device__ inline __half2 hmax2_(__half2 a, __half2 b) {
  __half2 c;
  c.x = __hgt(a.x, b.x) ? a.x : b.x;
  c.y = __hgt(a.y, b.y) ? a.y : b.y;
  return c;
}

// ---------------------------------------------------------------------------
// NODE ORDERING: base-major. Global row of (base node nb, graph g) = nb*128+g.
// ---------------------------------------------------------------------------

// Bucket-duty arguments (all 3 layers' base-graph CSR builds, done by the
// first few blocks of l0_fused — removes a separate launch; R18-verified).
struct BktArgs {
  const int* esrc[3]; const int* edst[3]; const int* cl[3];
  int Eb[3]; int est[3];
  int* bdeg[3]; int* bccnt[3]; int* bebkt[3]; int* bcbkt[3];
};

// Layer-0 fused: h = x @ W (fp16 out, base-major rows) + attention dots,
// plus base-graph bucketing in the first nBkt blocks.
__global__ __launch_bounds__(256) void l0_fused(
    const float* __restrict__ x, const float* __restrict__ W,
    const float* __restrict__ asv, const float* __restrict__ adv,
    unsigned short* __restrict__ h, float* __restrict__ ssrc,
    float* __restrict__ sdst, int N, int Nb0, BktArgs bk, int nBkt) {
  if (blockIdx.x < (unsigned)nBkt) {
    const int NbA[3] = {706, 512, 256};
    int i = blockIdx.x * 256 + threadIdx.x;
#pragma unroll
    for (int L = 0; L < 3; L++) {
      if (i < bk.Eb[L]) {
        int d = bk.edst[L][i];
        int slot = atomicAdd(&bk.bdeg[L][d], 1);
        if (slot < bk.est[L]) bk.bebkt[L][d * bk.est[L] + slot] = bk.esrc[L][i];
      }
      if (i < NbA[L]) {
        int c = bk.cl[L][i];
        int slot = atomicAdd(&bk.bccnt[L][c], 1);
        if (slot < MAXMEM) bk.bcbkt[L][c * MAXMEM + slot] = i;
      }
    }
  }
  int wid = (blockIdx.x * 256 + threadIdx.x) >> 6;  // nb*128+g
  int lane = threadIdx.x & 63;
  if (wid >= N) return;
  int nb = wid >> 7, g = wid & 127;
  const float* xr = x + ((size_t)g * Nb0 + nb) * 3;  // reference is graph-major
  float x0 = xr[0], x1 = xr[1], x2 = xr[2];
  int c = lane * 4;
  float4 w0 = *(const float4*)(W + c);
  float4 w1 = *(const float4*)(W + 256 + c);
  float4 w2 = *(const float4*)(W + 512 + c);
  float4 hv;
  hv.x = fmaf(x0, w0.x, fmaf(x1, w1.x, x2 * w2.x));
  hv.y = fmaf(x0, w0.y, fmaf(x1, w1.y, x2 * w2.y));
  hv.z = fmaf(x0, w0.z, fmaf(x1, w1.z, x2 * w2.z));
  hv.w = fmaf(x0, w0.w, fmaf(x1, w1.w, x2 * w2.w));
  ((ushort4*)(h + (size_t)wid * DIM))[lane] =
      make_ushort4(f2h(hv.x), f2h(hv.y), f2h(hv.z), f2h(hv.w));
  float4 a1 = ((const float4*)asv)[lane];
  float4 a2 = ((const float4*)adv)[lane];
  float d1 = hv.x * a1.x + hv.y * a1.y + hv.z * a1.z + hv.w * a1.w;
  float d2 = hv.x * a2.x + hv.y * a2.y + hv.z * a2.z + hv.w * a2.w;
  for (int o = 32; o > 0; o >>= 1) {
    d1 += __shfl_down(d1, o);
    d2 += __shfl_down(d2, o);
  }
  if (lane == 0) { ssrc[wid] = d1; sdst[wid] = d2; }
}

// ---------------------------------------------------------------------------
// Weight prep: fold normalization into W (fp16 Wt transposed + cvec).
__global__ __launch_bounds__(256) void prep_k(
    const float* __restrict__ W, const float* __restrict__ sums,
    const float* __restrict__ sqs, float invN,
    unsigned short* __restrict__ Wt, float* __restrict__ cvec) {
  int n = blockIdx.x;
  int k = threadIdx.x;
  float mu = sums[k] * invN;
  float var = sqs[k] * invN - mu * mu;
  float istd = rsqrtf(var + 1e-5f);
  float w = W[(size_t)k * 256 + n] * istd;
  Wt[(size_t)n * 256 + k] = f2h(w);
  __shared__ float red[256];
  red[k] = mu * w;
  __syncthreads();
  for (int s = 128; s > 0; s >>= 1) {
    if (k < s) red[k] += red[k + s];
    __syncthreads();
  }
  if (k == 0) cvec[n] = -red[0];
}

// ---------------------------------------------------------------------------
// MFMA fp16 GEMM + fused attention dots. 32-row waves (2 A-frags per B-frag).
__global__ __launch_bounds__(256) void gemm_mfma(
    const unsigned short* __restrict__ A, const unsigned short* __restrict__ Wt,
    const float* __restrict__ cvec, const float* __restrict__ asv,
    const float* __restrict__ adv, unsigned short* __restrict__ H,
    float* __restrict__ ssrc, float* __restrict__ sdst, int M) {
  __shared__ unsigned short Bs[2][256 * 32];  // 16 KB per buffer
  int tid = threadIdx.x;
  int wave = tid >> 6, lane = tid & 63;
  int m0 = blockIdx.x * 128 + wave * 32;
  int row = lane & 15, quad = lane >> 4;

#pragma unroll
  for (int i = 0; i < 4; i++) {
    int c = i * 256 + tid;
    f16x8 v = *(const f16x8*)(const void*)(Wt + (size_t)(c >> 2) * 256 + (c & 3) * 8);
    *(f16x8*)(void*)(&Bs[0][c * 8]) = v;
  }
  __syncthreads();

  const unsigned short* Ap = A + (size_t)(m0 + row) * 256 + quad * 8;
  f32x4 acc[2][16] = {};
  for (int j = 0; j < 8; j++) {
    f16x8 pf[4];
    if (j < 7) {
#pragma unroll
      for (int i = 0; i < 4; i++) {
        int c = i * 256 + tid;
        pf[i] = *(const f16x8*)(const void*)(Wt + (size_t)(c >> 2) * 256 +
                                             (j + 1) * 32 + (c & 3) * 8);
      }
    }
    f16x8 a0 = *(const f16x8*)(const void*)(Ap + j * 32);
    f16x8 a1 = *(const f16x8*)(const void*)(Ap + 16 * 256 + j * 32);
    const unsigned short* bs = Bs[j & 1];
#pragma unroll
    for (int nt = 0; nt < 16; nt++) {
      f16x8 b = *(const f16x8*)(const void*)(bs + (nt * 16 + row) * 32 + quad * 8);
      acc[0][nt] = __builtin_amdgcn_mfma_f32_16x16x32_f16(a0, b, acc[0][nt], 0, 0, 0);
      acc[1][nt] = __builtin_amdgcn_mfma_f32_16x16x32_f16(a1, b, acc[1][nt], 0, 0, 0);
    }
    if (j < 7) {
#pragma unroll
      for (int i = 0; i < 4; i++) {
        int c = i * 256 + tid;
        *(f16x8*)(void*)(&Bs[(j + 1) & 1][c * 8]) = pf[i];
      }
    }
    __syncthreads();
  }

  float sav[16], sdv[16], cv[16];
#pragma unroll
  for (int nt = 0; nt < 16; nt++) {
    sav[nt] = asv[nt * 16 + row];
    sdv[nt] = adv[nt * 16 + row];
    cv[nt] = cvec[nt * 16 + row];
  }
#pragma unroll
  for (int sub = 0; sub < 2; sub++)
#pragma unroll
    for (int r = 0; r < 4; r++) {
      int mm = m0 + sub * 16 + quad * 4 + r;
      unsigned short* out = H + (size_t)mm * 256 + row;
      float d1 = 0.f, d2 = 0.f;
#pragma unroll
      for (int nt = 0; nt < 16; nt++) {
        float hv = acc[sub][nt][r] + cv[nt];
        out[nt * 16] = f2h(hv);
        d1 = fmaf(hv, sav[nt], d1);
        d2 = fmaf(hv, sdv[nt], d2);
      }
      for (int o = 1; o < 16; o <<= 1) {
        d1 += __shfl_xor(d1, o);
        d2 += __shfl_xor(d2, o);
      }
      if (row == 0) { ssrc[mm] = d1; sdst[mm] = d2; }
    }
}

// ---------------------------------------------------------------------------
// FUSED: edge softmax (fp32, in LDS) + GAT aggregation + bias + relu +
// cluster max-pool, graph-batched. Block = (base cluster c, 8-graph set).
__global__ __launch_bounds__(256) void gat_fused(
    const unsigned short* __restrict__ h, const int* __restrict__ bdeg,
    const int* __restrict__ bebkt, int estride,
    const int* __restrict__ bccnt, const int* __restrict__ bcbkt,
    const float* __restrict__ ssrc, const float* __restrict__ sdst,
    const float* __restrict__ bias, unsigned short* __restrict__ pooled,
    int Mb, int lgMb) {
  __shared__ float pLDS[MAXDEG * 8];  // p[j][g_local], fp32
  __shared__ float psum[8];
  int b = blockIdx.x;                 // grid = Mb * 16
  int x = b & 7, t = b >> 3;
  int c = t & (Mb - 1);
  int set = x + 8 * (t >> lgMb);      // 0..15, pinned: b%8 == set%8
  int tid = threadIdx.x;
  int gl = tid >> 5;                  // graph within set (0..7)
  int ch = tid & 31;                  // channel chunk (8 fp16 = 16 B)
  int g = set * 8 + gl;
  int nm = bccnt[c]; if (nm > MAXMEM) nm = MAXMEM;
  float4 bf0 = *(const float4*)(bias + ch * 8);
  float4 bf1 = *(const float4*)(bias + ch * 8 + 4);
  __half2 hb[4] = {__floats2half2_rn(bf0.x, bf0.y), __floats2half2_rn(bf0.z, bf0.w),
                   __floats2half2_rn(bf1.x, bf1.y), __floats2half2_rn(bf1.z, bf1.w)};
  __half2 z = __float2half2_rn(0.f);
  __half2 best[4] = {z, z, z, z};     // relu folded via 0-init
  for (int mi = 0; mi < nm; mi++) {
    int nb = __builtin_amdgcn_readfirstlane(bcbkt[c * MAXMEM + mi]);
    int deg = __builtin_amdgcn_readfirstlane(bdeg[nb]);
    if (deg > estride) deg = estride;
    const int* bk = bebkt + nb * estride;
    if (tid < 8) psum[tid] = 0.f;
    __syncthreads();
    for (int jj = tid; jj < deg * 8; jj += 256) {
      int j = jj >> 3, gi = jj & 7;
      int g2 = set * 8 + gi;
      int s = bk[j];
      float tt = ssrc[s * 128 + g2] + sdst[nb * 128 + g2];
      tt = tt > 0.f ? tt : 0.2f * tt;  // leaky_relu 0.2
      float p = __expf(tt);
      pLDS[jj] = p;
      atomicAdd(&psum[gi], p);
    }
    __syncthreads();
    float inv = 1.f / psum[gl];        // deg >= 1 (self-loop)
    __half2 acc[4] = {z, z, z, z};
    int j = 0;
    for (; j + 4 <= deg; j += 4) {
      int4 ss = *(const int4*)(bk + j);                    // broadcast 16B
      __half2 hq0 = __float2half2_rn(pLDS[(j + 0) * 8 + gl] * inv);
      __half2 hq1 = __float2half2_rn(pLDS[(j + 1) * 8 + gl] * inv);
      __half2 hq2 = __float2half2_rn(pLDS[(j + 2) * 8 + gl] * inv);
      __half2 hq3 = __float2half2_rn(pLDS[(j + 3) * 8 + gl] * inv);
      uint4 v0 = *(const uint4*)(h + ((size_t)ss.x * 128 + g) * DIM + ch * 8);
      uint4 v1 = *(const uint4*)(h + ((size_t)ss.y * 128 + g) * DIM + ch * 8);
      uint4 v2 = *(const uint4*)(h + ((size_t)ss.z * 128 + g) * DIM + ch * 8);
      uint4 v3 = *(const uint4*)(h + ((size_t)ss.w * 128 + g) * DIM + ch * 8);
      union { uint4 u; __half2 p[4]; } u0, u1, u2, u3;
      u0.u = v0; u1.u = v1; u2.u = v2; u3.u = v3;
#pragma unroll
      for (int i = 0; i < 4; i++) {
        acc[i] = __hfma2(u0.p[i], hq0, acc[i]);
        acc[i] = __hfma2(u1.p[i], hq1, acc[i]);
        acc[i] = __hfma2(u2.p[i], hq2, acc[i]);
        acc[i] = __hfma2(u3.p[i], hq3, acc[i]);
      }
    }
    for (; j < deg; j++) {
      int s = bk[j];
      __half2 hq = __float2half2_rn(pLDS[j * 8 + gl] * inv);
      uint4 v0 = *(const uint4*)(h + ((size_t)s * 128 + g) * DIM + ch * 8);
      union { uint4 u; __half2 p[4]; } u0; u0.u = v0;
#pragma unroll
      for (int i = 0; i < 4; i++) acc[i] = __hfma2(u0.p[i], hq, acc[i]);
    }
#pragma unroll
    for (int i = 0; i < 4; i++)
      best[i] = hmax2_(best[i], __hadd2(acc[i], hb[i]));
    __syncthreads();  // protect pLDS/psum before next member overwrites
  }
  union { uint4 u; __half2 p[4]; } o;
#pragma unroll
  for (int i = 0; i < 4; i++) o.p[i] = best[i];
  *(uint4*)(pooled + ((size_t)c * 128 + g) * DIM + ch * 8) = o.u;
}

// ---------------------------------------------------------------------------
// Channel sums/sq-sums over M rows. Thread = (row-group rg, channel-chunk ch).
// Grid 1024 (R18 showed 512-block version latency-bound at 9% occupancy).
__global__ __launch_bounds__(256) void stats_k(
    const unsigned short* __restrict__ x, float* __restrict__ sums,
    float* __restrict__ sqs, int M) {
  int tid = threadIdx.x;
  int ch = tid & 31;   // 8 channels: ch*8 .. ch*8+7
  int rg = tid >> 5;   // row group 0..7
  float s[8] = {}, q[8] = {};
  for (int r = blockIdx.x * 8 + rg; r < M; r += gridDim.x * 8) {
    uint4 v = *(const uint4*)(x + (size_t)r * DIM + ch * 8);
    union { uint4 u; __half2 p[4]; } uu; uu.u = v;
#pragma unroll
    for (int i = 0; i < 4; i++) {
      float2 f = __half22float2(uu.p[i]);
      s[2 * i]     += f.x; q[2 * i]     = fmaf(f.x, f.x, q[2 * i]);
      s[2 * i + 1] += f.y; q[2 * i + 1] = fmaf(f.y, f.y, q[2 * i + 1]);
    }
  }
  __shared__ float sm[512];
  sm[tid] = 0.f; sm[tid + 256] = 0.f;
  __syncthreads();
#pragma unroll
  for (int i = 0; i < 8; i++) {
    atomicAdd(&sm[ch * 8 + i], s[i]);
    atomicAdd(&sm[256 + ch * 8 + i], q[i]);
  }
  __syncthreads();
  atomicAdd(&sums[tid], sm[tid]);
  atomicAdd(&sqs[tid], sm[tid + 256]);
}

// Final normalize: fp16 pooled (base-major) -> fp32 d_out (graph-major).
__global__ void norm_out(const unsigned short* __restrict__ xin,
                         float* __restrict__ xout,
                         const float* __restrict__ sums, const float* __restrict__ sqs,
                         float invN, int Mb, int total) {
  int idx = blockIdx.x * 256 + threadIdx.x;
  if (idx >= total) return;
  int ch = idx & 255;
  int r = idx >> 8;            // r = c*128 + g
  int g = r & 127, c = r >> 7;
  float mu = sums[ch] * invN;
  float var = sqs[ch] * invN - mu * mu;
  float v = (h2f(xin[idx]) - mu) * rsqrtf(var + 1e-5f);
  xout[((size_t)g * Mb + c) * 256 + ch] = v;
}

// ---------------------------------------------------------------------------
extern "C" void kernel_launch(void* const* d_in, const int* in_sizes, int n_in,
                              void* d_out, int out_size, void* d_ws, size_t ws_size,
                              hipStream_t stream) {
  const int B = 128;
  const int Nb[4] = {706, 512, 256, 128};          // base-graph sizes
  const int Ns[4] = {128 * 706, 128 * 512, 128 * 256, 128 * 128};
  const int lgMb[3] = {9, 8, 7};                   // log2(Nb[L+1])
  const int EST[3] = {64, 160, 288};               // base in-degree strides

  int iW[3], iA[3], iD[3], iB_[3], iE[3], iC[3];
  if (in_sizes[2] == 256) {  // dict order
    for (int i = 0; i < 3; i++) {
      iW[i] = 1 + 6 * i; iA[i] = 2 + 6 * i; iD[i] = 3 + 6 * i;
      iB_[i] = 4 + 6 * i; iE[i] = 5 + 6 * i; iC[i] = 6 + 6 * i;
    }
  } else {
    for (int i = 0; i < 3; i++) {
      iW[i] = 1 + i; iA[i] = 4 + i; iD[i] = 7 + i;
      iB_[i] = 10 + i; iE[i] = 13 + i; iC[i] = 16 + i;
    }
  }
  int E[3];
  for (int i = 0; i < 3; i++) E[i] = in_sizes[iE[i]] / 2;

  int bebktOff[3], bcbktOff[3];
  size_t bebktTot = 0, bcbktTot = 0;
  for (int i = 0; i < 3; i++) {
    bebktOff[i] = (int)bebktTot; bebktTot += (size_t)Nb[i] * EST[i];
    bcbktOff[i] = (int)bcbktTot; bcbktTot += (size_t)Nb[i + 1] * MAXMEM;
  }

  char* wsp = (char*)d_ws;
  size_t o = 0;
  auto alloc = [&](size_t bytes) -> void* {
    void* p = wsp + o;
    o = (o + bytes + 255) & ~(size_t)255;
    return p;
  };
  unsigned short* h      = (unsigned short*)alloc((size_t)Ns[0] * DIM * 2);  // 46 MB
  unsigned short* pooled = (unsigned short*)alloc((size_t)Ns[1] * DIM * 2);  // 33.5 MB
  float* ssrc   = (float*)alloc((size_t)Ns[0] * 4);
  float* sdst   = (float*)alloc((size_t)Ns[0] * 4);
  // Zeroed region: statbuf + bmeta (single memset).
  float* statbuf= (float*)alloc(3 * 512 * 4);
  int*   bmeta  = (int*)alloc((size_t)3 * (Nb[0] + Nb[1]) * 4);  // deg+ccnt x3
  char*  zend   = wsp + o;
  int*   bebkt  = (int*)alloc(bebktTot * 4);                     // ~800 KB
  int*   bcbkt  = (int*)alloc(bcbktTot * 4);                     // ~57 KB
  unsigned short* Wt = (unsigned short*)alloc(256 * 256 * 2);
  float* cvec   = (float*)alloc(256 * 4);
  (void)ws_size; (void)n_in; (void)out_size;

  const float* xin = (const float*)d_in[0];

  hipMemsetAsync(statbuf, 0, (size_t)(zend - (char*)statbuf), stream);

  // Bucket-duty args for l0_fused's first blocks.
  BktArgs ba;
  int maxNeed = 0;
  for (int L = 0; L < 3; L++) {
    int Eb = E[L] / B;
    ba.esrc[L] = (const int*)d_in[iE[L]];
    ba.edst[L] = ba.esrc[L] + E[L];
    ba.cl[L]   = (const int*)d_in[iC[L]];
    ba.Eb[L] = Eb; ba.est[L] = EST[L];
    ba.bdeg[L]  = bmeta + L * (Nb[0] + Nb[1]);
    ba.bccnt[L] = ba.bdeg[L] + Nb[L];
    ba.bebkt[L] = bebkt + bebktOff[L];
    ba.bcbkt[L] = bcbkt + bcbktOff[L];
    int need = Eb > Nb[L] ? Eb : Nb[L];
    if (need > maxNeed) maxNeed = need;
  }
  int nBkt = (maxNeed + 255) / 256;

  // L0: h + dots + bucketing (one kernel).
  l0_fused<<<(Ns[0] + 3) / 4, 256, 0, stream>>>(
      xin, (const float*)d_in[iW[0]], (const float*)d_in[iA[0]],
      (const float*)d_in[iD[0]], h, ssrc, sdst, Ns[0], Nb[0], ba, nBkt);

  for (int L = 0; L < 3; L++) {
    int M = Ns[L + 1];
    const float* av = (const float*)d_in[iA[L]];
    const float* dv = (const float*)d_in[iD[L]];
    const float* bv = (const float*)d_in[iB_[L]];
    int* bdeg = bmeta + L * (Nb[0] + Nb[1]);
    int* bccnt = bdeg + Nb[L];
    int* beb = bebkt + bebktOff[L];
    int* bcb = bcbkt + bcbktOff[L];
    float* sums = statbuf + L * 512;
    float* sqs  = sums + 256;

    if (L > 0) {
      float* psums = statbuf + (L - 1) * 512;
      prep_k<<<256, 256, 0, stream>>>((const float*)d_in[iW[L]], psums,
                                      psums + 256, 1.0f / (float)Ns[L],
                                      Wt, cvec);
      gemm_mfma<<<Ns[L] / 128, 256, 0, stream>>>(pooled, Wt, cvec, av, dv,
                                                 h, ssrc, sdst, Ns[L]);
    }

    gat_fused<<<Nb[L + 1] * 16, 256, 0, stream>>>(h, bdeg, beb, EST[L],
                                                  bccnt, bcb, ssrc, sdst, bv,
                                                  pooled, Nb[L + 1], lgMb[L]);

    stats_k<<<1024, 256, 0, stream>>>(pooled, sums, sqs, M);
  }

  norm_out<<<((size_t)Ns[3] * DIM + 255) / 256, 256, 0, stream>>>(
      pooled, (float*)d_out, statbuf + 2 * 512, statbuf + 2 * 512 + 256,
      1.0f / (float)Ns[3], Nb[3], Ns[3] * DIM);
}